// Round 1
// baseline (731.597 us; speedup 1.0000x reference)
//
#include <hip/hip_runtime.h>

namespace {

typedef float v2f __attribute__((ext_vector_type(2)));

constexpr int T_SEQ = 2048;
constexpr int B_SZ  = 512;
constexpr int C_IN  = 8;
constexpr int H_SZ  = 20;
constexpr int P_LEN = 16;                 // steps per phase (barrier period)
constexpr int N_PH  = T_SEQ / P_LEN;      // 128 phases
constexpr int RING  = 2 * P_LEN;          // 32-slot handoff rings
constexpr float LOG2E = 1.44269504088896340736f;
constexpr float M2 = -2.0f * LOG2E;       // tanh exp2 scale

__device__ __forceinline__ float rlane(float v, int lane) {
  return __int_as_float(__builtin_amdgcn_readlane(__float_as_int(v), lane));
}

template<int S>
__device__ __forceinline__ float quad_bcast(float v) {
  return __int_as_float(__builtin_amdgcn_update_dpp(
      __float_as_int(v), __float_as_int(v), S * 0x55, 0xF, 0xF, true));
}

__device__ __forceinline__ v2f fma2(v2f a, v2f b, v2f c) {
  return __builtin_elementwise_fma(a, b, c);   // -> v_pk_fma_f32
}
__device__ __forceinline__ v2f splat2(float s) { v2f r; r.x = s; r.y = s; return r; }
__device__ __forceinline__ v2f zero2() { v2f r; r.x = 0.f; r.y = 0.f; return r; }

// Elementwise activation on both gate sets: sigmoid (g!=2) / tanh (g==2).
__device__ __forceinline__ v2f act2(v2f a, float cm, float am, float ad) {
  float ex = __builtin_amdgcn_exp2f(a.x * cm);
  float ey = __builtin_amdgcn_exp2f(a.y * cm);
  float sx = __builtin_amdgcn_rcpf(1.0f + ex);
  float sy = __builtin_amdgcn_rcpf(1.0f + ey);
  v2f r; r.x = __fmaf_rn(sx, am, ad); r.y = __fmaf_rn(sy, am, ad);
  return r;
}

__global__ __attribute__((amdgpu_flat_work_group_size(128, 128),
                          amdgpu_waves_per_eu(1, 1)))
void lstm2_pk(const float* __restrict__ x,
              const float* __restrict__ Wih0, const float* __restrict__ Whh0,
              const float* __restrict__ bih0, const float* __restrict__ bhh0,
              const float* __restrict__ Wih1, const float* __restrict__ Whh1,
              const float* __restrict__ bih1, const float* __restrict__ bhh1,
              float* __restrict__ out)
{
  // h0 handoff ring: 32 steps (2 phases), 20 floats per slot (80 B, 16-aligned).
  __shared__ __align__(16) float hbuf[RING][H_SZ];
  // NEW: per-lane v2f partial of layer-1 input dot (k=0..9), 32 x 64 x 8 B = 16 KB.
  __shared__ __align__(16) v2f   pbuf[RING][64];
  // x staging: double buffer, 16 steps x 8 ch = 128 floats per phase.
  __shared__ __align__(16) float xbuf[2][P_LEN * C_IN];

  const int tid = threadIdx.x;
  const int wv  = tid >> 6;          // 0 = layer-0 wave, 1 = layer-1 wave
  const int l   = tid & 63;
  const int b   = blockIdx.x;
  const int k1  = l >> 2;            // 0..15
  const int g   = l & 3;             // gate slot: 0=i 1=f 2=g 3=o
  const int k2  = 16 + (k1 & 3);     // 16..19 (replicated)
  const int j1  = g * H_SZ + k1;
  const int j2  = g * H_SZ + k2;

  const bool  isg = (g == 2);
  const float cm  = isg ? (-2.0f * LOG2E) : (-LOG2E);
  const float am  = isg ?  2.0f : 1.0f;
  const float ad  = isg ? -1.0f : 0.0f;

  if (wv == 0) {
    // ================= layer-0 producer wave =================
    v2f wx1[C_IN / 2], wx2[C_IN / 2];  // Wih0 rows j1/j2, k-packed
    v2f wh[H_SZ];                      // {Whh0[j1][k], Whh0[j2][k]} gate-set packed
    v2f wp[10];                        // NEW: {Wih1[j1][k], Wih1[j2][k]}, k=0..9
#pragma unroll
    for (int t = 0; t < C_IN / 2; ++t) {
      wx1[t].x = Wih0[j1 * C_IN + 2 * t]; wx1[t].y = Wih0[j1 * C_IN + 2 * t + 1];
      wx2[t].x = Wih0[j2 * C_IN + 2 * t]; wx2[t].y = Wih0[j2 * C_IN + 2 * t + 1];
    }
#pragma unroll
    for (int k = 0; k < H_SZ; ++k) {
      wh[k].x = Whh0[j1 * H_SZ + k]; wh[k].y = Whh0[j2 * H_SZ + k];
    }
#pragma unroll
    for (int k = 0; k < 10; ++k) {
      wp[k].x = Wih1[j1 * H_SZ + k]; wp[k].y = Wih1[j2 * H_SZ + k];
    }
    v2f bias2; bias2.x = bih0[j1] + bhh0[j1]; bias2.y = bih0[j2] + bhh0[j2];

    float h_s[H_SZ];                   // wave-uniform broadcast of h(t-1) (SGPRs)
#pragma unroll
    for (int k = 0; k < H_SZ; ++k) h_s[k] = 0.f;
    float ha = 0.f, ca = 0.f, hb = 0.f, cb = 0.f;

    // Per-lane x slice: element e in [0,128) of a phase -> step e>>3, channel e&7.
    const float* xl = x + (size_t)(l >> 3) * (B_SZ * C_IN) + b * C_IN + (l & 7);
    const size_t halfph = (size_t)8 * B_SZ * C_IN;
    const size_t phstr  = (size_t)P_LEN * B_SZ * C_IN;

    // Bootstrap: phase 0 committed now; phase 1 stays in flight a whole phase.
    {
      float v0 = xl[0], v1 = xl[halfph];
      xbuf[0][l] = v0; xbuf[0][64 + l] = v1;
    }
    float n0 = xl[phstr], n1 = xl[phstr + halfph];

    for (int p = 0; p <= N_PH; ++p) {
      if (p < N_PH) {
        const int buf = p & 1;
        float4 xc0 = ((const float4*)&xbuf[buf][0])[0];
        float4 xc1 = ((const float4*)&xbuf[buf][0])[1];
        for (int j = 0; j < P_LEN; ++j) {
          const int n = p * P_LEN + j;
          v2f xp[4];
          xp[0].x = xc0.x; xp[0].y = xc0.y; xp[1].x = xc0.z; xp[1].y = xc0.w;
          xp[2].x = xc1.x; xp[2].y = xc1.y; xp[3].x = xc1.z; xp[3].y = xc1.w;
          if (j + 1 < P_LEN) {           // one-step-ahead x prefetch (LDS bcast)
            xc0 = ((const float4*)&xbuf[buf][(j + 1) * C_IN])[0];
            xc1 = ((const float4*)&xbuf[buf][(j + 1) * C_IN])[1];
          }

          // Input dot first (independent of h, x prefetched -> hoistable).
          v2f X1 = zero2(), X2 = zero2();
#pragma unroll
          for (int t = 0; t < C_IN / 2; ++t) {
            X1 = fma2(wx1[t], xp[t], X1);
            X2 = fma2(wx2[t], xp[t], X2);
          }
          v2f Xs; Xs.x = X1.x + X1.y; Xs.y = X2.x + X2.y;

          // Recurrent dot: 4 accumulators, chain depth 5, tail = 2 pk-adds.
          v2f A0 = bias2, A1 = Xs, A2 = zero2(), A3 = zero2();
#pragma unroll
          for (int k = 0; k < H_SZ; k += 4) {
            A0 = fma2(wh[k],     splat2(h_s[k]),     A0);
            A1 = fma2(wh[k + 1], splat2(h_s[k + 1]), A1);
            A2 = fma2(wh[k + 2], splat2(h_s[k + 2]), A2);
            A3 = fma2(wh[k + 3], splat2(h_s[k + 3]), A3);
          }
          v2f A = (A0 + A1) + (A2 + A3);

          v2f act = act2(A, cm, am, ad);
          float iv = quad_bcast<0>(act.x), fv = quad_bcast<1>(act.x);
          float gv = quad_bcast<2>(act.x), ov = quad_bcast<3>(act.x);
          ca = __fmaf_rn(fv, ca, iv * gv);
          {
            float e = __builtin_amdgcn_exp2f(ca * M2);
            float r = __builtin_amdgcn_rcpf(1.0f + e);
            ha = __fmaf_rn(r, ov + ov, -ov);     // ov*tanh(ca), fused
          }
          iv = quad_bcast<0>(act.y); fv = quad_bcast<1>(act.y);
          gv = quad_bcast<2>(act.y); ov = quad_bcast<3>(act.y);
          cb = __fmaf_rn(fv, cb, iv * gv);
          {
            float e = __builtin_amdgcn_exp2f(cb * M2);
            float r = __builtin_amdgcn_rcpf(1.0f + e);
            hb = __fmaf_rn(r, ov + ov, -ov);
          }

          const int slot = n & (RING - 1);
          if (g == 0) {
            hbuf[slot][k1] = ha;
            if (k1 < 4) hbuf[slot][16 + k1] = hb;
          }

          // Tail: broadcast h(t) once; reused by next step's dot AND the
          // layer-1 partial (free readlanes for the k<10 half of L1's y-dot).
#pragma unroll
          for (int k = 0; k < 16; ++k) h_s[k] = rlane(ha, 4 * k);
#pragma unroll
          for (int k = 0; k < 4; ++k)  h_s[16 + k] = rlane(hb, 4 * k);

          v2f P0 = zero2(), P1 = zero2();
#pragma unroll
          for (int k = 0; k < 10; k += 2) {
            P0 = fma2(wp[k],     splat2(h_s[k]),     P0);
            P1 = fma2(wp[k + 1], splat2(h_s[k + 1]), P1);
          }
          pbuf[slot][l] = P0 + P1;     // race-free: written before phase barrier
        }
        // Commit next phase's x (in flight ~16 steps); issue load for p+2.
        if (p + 1 < N_PH) { xbuf[(p + 1) & 1][l] = n0; xbuf[(p + 1) & 1][64 + l] = n1; }
        if (p + 2 < N_PH) {
          n0 = xl[(size_t)(p + 2) * phstr];
          n1 = xl[(size_t)(p + 2) * phstr + halfph];
        }
      }
      __syncthreads();   // 129 barriers total, both waves
    }
  } else {
    // ================= layer-1 consumer wave (lags one phase) =================
    v2f wy1[5], wy2[5];                // Wih1 rows j1/j2, k-packed, k=10..19 only
#pragma unroll
    for (int t = 0; t < 5; ++t) {
      wy1[t].x = Wih1[j1 * H_SZ + 10 + 2 * t]; wy1[t].y = Wih1[j1 * H_SZ + 11 + 2 * t];
      wy2[t].x = Wih1[j2 * H_SZ + 10 + 2 * t]; wy2[t].y = Wih1[j2 * H_SZ + 11 + 2 * t];
    }
    v2f wq[H_SZ];                      // {Whh1[j1][k], Whh1[j2][k]} gate-set packed
#pragma unroll
    for (int k = 0; k < H_SZ; ++k) {
      wq[k].x = Whh1[j1 * H_SZ + k]; wq[k].y = Whh1[j2 * H_SZ + k];
    }
    v2f bias2; bias2.x = bih1[j1] + bhh1[j1]; bias2.y = bih1[j2] + bhh1[j2];

    float h_s[H_SZ];
#pragma unroll
    for (int k = 0; k < H_SZ; ++k) h_s[k] = 0.f;
    float ha = 0.f, ca = 0.f, hb = 0.f, cb = 0.f;
    float* op = out + b * H_SZ;

    auto stepW1 = [&](const float4 (&yq)[3], v2f P) {
      // y-stream: only k=10..19 remain here (k<10 arrives precomputed in P).
      v2f yp[5];
      yp[0].x = yq[0].z; yp[0].y = yq[0].w;    // y10,y11
      yp[1].x = yq[1].x; yp[1].y = yq[1].y;    // y12,y13
      yp[2].x = yq[1].z; yp[2].y = yq[1].w;    // y14,y15
      yp[3].x = yq[2].x; yp[3].y = yq[2].y;    // y16,y17
      yp[4].x = yq[2].z; yp[4].y = yq[2].w;    // y18,y19
      v2f Y1a = zero2(), Y1b = zero2(), Y2a = zero2(), Y2b = zero2();
      Y1a = fma2(wy1[0], yp[0], Y1a); Y2a = fma2(wy2[0], yp[0], Y2a);
      Y1b = fma2(wy1[1], yp[1], Y1b); Y2b = fma2(wy2[1], yp[1], Y2b);
      Y1a = fma2(wy1[2], yp[2], Y1a); Y2a = fma2(wy2[2], yp[2], Y2a);
      Y1b = fma2(wy1[3], yp[3], Y1b); Y2b = fma2(wy2[3], yp[3], Y2b);
      Y1a = fma2(wy1[4], yp[4], Y1a); Y2a = fma2(wy2[4], yp[4], Y2a);
      v2f Y1 = Y1a + Y1b, Y2 = Y2a + Y2b;
      v2f Ys; Ys.x = Y1.x + Y1.y; Ys.y = Y2.x + Y2.y;

      // q-stream (h1 recurrence): 4 accumulators, inits carry bias/partial/y.
      v2f Q0 = bias2, Q1 = P, Q2 = Ys, Q3 = zero2();
#pragma unroll
      for (int k = 0; k < H_SZ; k += 4) {
        Q0 = fma2(wq[k],     splat2(h_s[k]),     Q0);
        Q1 = fma2(wq[k + 1], splat2(h_s[k + 1]), Q1);
        Q2 = fma2(wq[k + 2], splat2(h_s[k + 2]), Q2);
        Q3 = fma2(wq[k + 3], splat2(h_s[k + 3]), Q3);
      }
      v2f A = (Q0 + Q1) + (Q2 + Q3);

      v2f act = act2(A, cm, am, ad);
      float iv = quad_bcast<0>(act.x), fv = quad_bcast<1>(act.x);
      float gv = quad_bcast<2>(act.x), ov = quad_bcast<3>(act.x);
      ca = __fmaf_rn(fv, ca, iv * gv);
      {
        float e = __builtin_amdgcn_exp2f(ca * M2);
        float r = __builtin_amdgcn_rcpf(1.0f + e);
        ha = __fmaf_rn(r, ov + ov, -ov);
      }
      iv = quad_bcast<0>(act.y); fv = quad_bcast<1>(act.y);
      gv = quad_bcast<2>(act.y); ov = quad_bcast<3>(act.y);
      cb = __fmaf_rn(fv, cb, iv * gv);
      {
        float e = __builtin_amdgcn_exp2f(cb * M2);
        float r = __builtin_amdgcn_rcpf(1.0f + e);
        hb = __fmaf_rn(r, ov + ov, -ov);
      }

      if (g == 0) {
        op[k1] = ha;
        if (k1 < 4) op[16 + k1] = hb;
      }
      op += B_SZ * H_SZ;

      // Tail: broadcast h1(t) for next step's recurrence.
#pragma unroll
      for (int k = 0; k < 16; ++k) h_s[k] = rlane(ha, 4 * k);
#pragma unroll
      for (int k = 0; k < 4; ++k)  h_s[16 + k] = rlane(hb, 4 * k);
    };

    for (int p = 0; p <= N_PH; ++p) {
      if (p >= 1) {
        const int base = (p - 1) * P_LEN;
        float4 yA[3], yB[3]; v2f pA, pB;
        {
          const int s0 = base & (RING - 1);
          const float4* s = (const float4*)hbuf[s0];
          yA[0] = s[2]; yA[1] = s[3]; yA[2] = s[4];
          pA = pbuf[s0][l];
        }
        {
          const int s1 = (base + 1) & (RING - 1);
          const float4* s = (const float4*)hbuf[s1];
          yB[0] = s[2]; yB[1] = s[3]; yB[2] = s[4];
          pB = pbuf[s1][l];
        }
        for (int jj = 0; jj < P_LEN; jj += 2) {
          stepW1(yA, pA);
          if (jj + 2 < P_LEN) {        // reload issued now, consumed next-next step
            const int sn = (base + jj + 2) & (RING - 1);
            const float4* s = (const float4*)hbuf[sn];
            yA[0] = s[2]; yA[1] = s[3]; yA[2] = s[4];
            pA = pbuf[sn][l];
          }
          stepW1(yB, pB);
          if (jj + 3 < P_LEN) {
            const int sn = (base + jj + 3) & (RING - 1);
            const float4* s = (const float4*)hbuf[sn];
            yB[0] = s[2]; yB[1] = s[3]; yB[2] = s[4];
            pB = pbuf[sn][l];
          }
        }
      }
      __syncthreads();
    }
  }
}

} // namespace

extern "C" void kernel_launch(void* const* d_in, const int* in_sizes, int n_in,
                              void* d_out, int out_size, void* d_ws, size_t ws_size,
                              hipStream_t stream) {
  const float* x    = (const float*)d_in[0];
  const float* Wih0 = (const float*)d_in[1];
  const float* Whh0 = (const float*)d_in[2];
  const float* bih0 = (const float*)d_in[3];
  const float* bhh0 = (const float*)d_in[4];
  const float* Wih1 = (const float*)d_in[5];
  const float* Whh1 = (const float*)d_in[6];
  const float* bih1 = (const float*)d_in[7];
  const float* bhh1 = (const float*)d_in[8];
  float* out = (float*)d_out;

  hipLaunchKernelGGL(lstm2_pk, dim3(B_SZ), dim3(128), 0, stream,
                     x, Wih0, Whh0, bih0, bhh0, Wih1, Whh1, bih1, bhh1, out);
}